// Round 2
// baseline (266.582 us; speedup 1.0000x reference)
//
#include <hip/hip_runtime.h>
#include <hip/hip_bf16.h>
#include <stdint.h>
#include <stddef.h>

// Problem: B=2, S=2048, DM=1024, H=16, HD=64.
// out = ((k@Wk+bk) "swapped-attention" (q@Wq+bq, v@Wv+bv)) @ Wo + bo
// scores[b,c,h,q] = kp[b,c,h,:]·qp[b,q,h,:]; softmax over q; out_c = sum_q P * vp[q].

typedef __attribute__((ext_vector_type(4))) float f32x4;
typedef __attribute__((ext_vector_type(8))) short s16x8;
typedef __attribute__((ext_vector_type(4))) unsigned int u32x4;
typedef __attribute__((ext_vector_type(4))) unsigned short u16x4;

#define DEV static __device__ __forceinline__

DEV unsigned short f2bf(float x) {              // f32 -> bf16, round-to-nearest-even
  unsigned int u = __float_as_uint(x);
  u += 0x7FFF + ((u >> 16) & 1);
  return (unsigned short)(u >> 16);
}
DEV float bf2f(unsigned short h) { return __uint_as_float(((unsigned int)h) << 16); }

DEV f32x4 mfma16(s16x8 a, s16x8 b, f32x4 c) {
  return __builtin_amdgcn_mfma_f32_16x16x32_bf16(a, b, c, 0, 0, 0);
}
DEV f32x4 fzero() { f32x4 z; z[0]=0.f; z[1]=0.f; z[2]=0.f; z[3]=0.f; return z; }

// ---------------------------------------------------------------------------
// Kernel 1: weight f32 -> bf16 transpose.  W[k][n] (1024x1024) -> Wt[n][k] bf16
// ---------------------------------------------------------------------------
struct WArgs { const float* W[4]; unsigned short* Wt[4]; };

__global__ __launch_bounds__(256) void wtrans_kernel(WArgs a) {
  const float* W = a.W[blockIdx.z];
  unsigned short* Wt = a.Wt[blockIdx.z];
  const int n0 = blockIdx.x * 32, k0 = blockIdx.y * 32;
  __shared__ float t[32][33];
  const int tx = threadIdx.x & 31, ty = threadIdx.x >> 5;   // ty in [0,8)
#pragma unroll
  for (int i = 0; i < 4; ++i)
    t[ty + i*8][tx] = W[(size_t)(k0 + ty + i*8) * 1024 + n0 + tx];
  __syncthreads();
#pragma unroll
  for (int i = 0; i < 4; ++i)
    Wt[(size_t)(n0 + ty + i*8) * 1024 + k0 + tx] = f2bf(t[tx][ty + i*8]);
}

// ---------------------------------------------------------------------------
// Kernel 2: GEMM  C[M=4096][N=1024] = A(f32, split hi/lo bf16) @ Wt^T + bias
// 128x128 tile, 4 waves x (64x64), BK=32, 2 MFMAs (hi,lo) per fragment pair.
// mode 0: C bf16 row-major [4096][1024]
// mode 1: C bf16 transposed per-head: vpt[b][h][d][s]   (for V projection)
// mode 2: C f32 row-major (final output)
// ---------------------------------------------------------------------------
struct GArgs {
  const float* A[3];
  const unsigned short* Wt[3];
  const float* bias[3];
  void* C[3];
  int mode[3];
};

__global__ __launch_bounds__(256) void gemm_kernel(GArgs g) {
  const int z = blockIdx.z;
  const float* A = g.A[z];
  const unsigned short* Wt = g.Wt[z];
  const float* bias = g.bias[z];
  const int mode = g.mode[z];
  const int m0 = blockIdx.y * 128, n0 = blockIdx.x * 128;
  const int tid = threadIdx.x;
  const int lane = tid & 63, w = tid >> 6;
  const int wm = w >> 1, wn = w & 1;          // 2x2 wave grid
  const int lg = lane >> 4, lr = lane & 15;

  __shared__ __align__(16) unsigned short Ah[128][40];  // 32 + 8 pad (80B rows, 16B-aligned)
  __shared__ __align__(16) unsigned short Al[128][40];
  __shared__ __align__(16) unsigned short Bs[128][40];  // Wt tile [n][k]

  f32x4 acc[4][4];
#pragma unroll
  for (int i = 0; i < 4; ++i)
#pragma unroll
    for (int j = 0; j < 4; ++j) acc[i][j] = fzero();

  for (int kk = 0; kk < 1024; kk += 32) {
    __syncthreads();
    // stage A tile 128x32 f32 -> hi/lo bf16
#pragma unroll
    for (int i = 0; i < 4; ++i) {
      int id = tid + i * 256;                 // [0,1024)
      int row = id >> 3, seg = id & 7;
      f32x4 v = *(const f32x4*)(A + (size_t)(m0 + row) * 1024 + kk + seg * 4);
      u16x4 hi, lo;
#pragma unroll
      for (int j = 0; j < 4; ++j) {
        unsigned short hb = f2bf(v[j]);
        hi[j] = hb;
        lo[j] = f2bf(v[j] - bf2f(hb));
      }
      *(u16x4*)&Ah[row][seg * 4] = hi;
      *(u16x4*)&Al[row][seg * 4] = lo;
    }
    // stage Wt tile 128x32 bf16 (already transposed: contiguous in k)
#pragma unroll
    for (int i = 0; i < 2; ++i) {
      int id = tid + i * 256;                 // [0,512)
      int row = id >> 2, seg = id & 3;
      *(u32x4*)&Bs[row][seg * 8] =
          *(const u32x4*)(Wt + (size_t)(n0 + row) * 1024 + kk + seg * 8);
    }
    __syncthreads();

    s16x8 ah[4], al[4], bb[4];
#pragma unroll
    for (int mf = 0; mf < 4; ++mf) {
      ah[mf] = *(const s16x8*)&Ah[wm*64 + mf*16 + lr][lg * 8];
      al[mf] = *(const s16x8*)&Al[wm*64 + mf*16 + lr][lg * 8];
    }
#pragma unroll
    for (int nf = 0; nf < 4; ++nf)
      bb[nf] = *(const s16x8*)&Bs[wn*64 + nf*16 + lr][lg * 8];
#pragma unroll
    for (int mf = 0; mf < 4; ++mf)
#pragma unroll
      for (int nf = 0; nf < 4; ++nf) {
        acc[mf][nf] = mfma16(ah[mf], bb[nf], acc[mf][nf]);
        acc[mf][nf] = mfma16(al[mf], bb[nf], acc[mf][nf]);
      }
  }

  // epilogue: C/D layout col = lane&15, row = (lane>>4)*4 + reg
#pragma unroll
  for (int nf = 0; nf < 4; ++nf) {
    const int colg = n0 + wn*64 + nf*16 + lr;
    const float bi = bias[colg];
#pragma unroll
    for (int mf = 0; mf < 4; ++mf) {
      const int rowg0 = m0 + wm*64 + mf*16 + lg*4;
      if (mode == 0) {
        unsigned short* o = (unsigned short*)g.C[z];
#pragma unroll
        for (int r = 0; r < 4; ++r)
          o[(size_t)(rowg0 + r) * 1024 + colg] = f2bf(acc[mf][nf][r] + bi);
      } else if (mode == 1) {
        unsigned short* o = (unsigned short*)g.C[z];
        const int hh = colg >> 6, d = colg & 63;
        const int bb2 = rowg0 >> 11, s = rowg0 & 2047;
        u16x4 pk;
#pragma unroll
        for (int r = 0; r < 4; ++r) pk[r] = f2bf(acc[mf][nf][r] + bi);
        *(u16x4*)(o + ((size_t)((bb2*16 + hh)*64 + d)) * 2048 + s) = pk;
      } else {
        float* o = (float*)g.C[z];
#pragma unroll
        for (int r = 0; r < 4; ++r)
          o[(size_t)(rowg0 + r) * 1024 + colg] = acc[mf][nf][r] + bi;
      }
    }
  }
}

// ---------------------------------------------------------------------------
// Kernel 3: flash attention (swapped roles).  Per (b,h): rows = c (from kp),
// reduction axis j = q (from qp), values vp (staged from transposed vpt).
// Block: 64 c-rows, 4 waves x 16 rows. JBLK = 64. Online softmax.
// ---------------------------------------------------------------------------
__global__ __launch_bounds__(256) void attn_kernel(
    const unsigned short* __restrict__ kp, const unsigned short* __restrict__ qp,
    const unsigned short* __restrict__ vpt, float* __restrict__ aout) {
  const int bh = blockIdx.y;
  const int b = bh >> 4, h = bh & 15;
  const int r0 = blockIdx.x * 64;
  const int tid = threadIdx.x;
  const int lane = tid & 63, w = tid >> 6;
  const int lg = lane >> 4, lr = lane & 15;

  __shared__ __align__(16) unsigned short Ks[64][72];      // K_eff[j][d]
  __shared__ __align__(16) unsigned short Vs[64][72];      // V_eff^T[d][j]
  __shared__ __align__(16) unsigned short Ps[4][16][72];   // per-wave P tile

  // Q fragments (A-operand, M=16 rows) straight from global; 2 k-steps of d
  const unsigned short* qptr =
      kp + (size_t)(b*2048 + r0 + w*16 + lr) * 1024 + h*64 + lg*8;
  const s16x8 qf0 = *(const s16x8*)qptr;
  const s16x8 qf1 = *(const s16x8*)(qptr + 32);

  float m_run[4], l_run[4];
  f32x4 oacc[4];
#pragma unroll
  for (int r = 0; r < 4; ++r) { m_run[r] = -1e30f; l_run[r] = 0.f; }
#pragma unroll
  for (int d = 0; d < 4; ++d) oacc[d] = fzero();

  for (int jt = 0; jt < 32; ++jt) {
    const int j0 = jt * 64;
    __syncthreads();
    {
      const unsigned short* kbase = qp + (size_t)(b*2048 + j0) * 1024 + h*64;
      const unsigned short* vbase = vpt + ((size_t)(b*16 + h) * 64) * 2048 + j0;
#pragma unroll
      for (int i = 0; i < 2; ++i) {
        int id = tid + i*256, row = id >> 3, seg = id & 7;
        *(u32x4*)&Ks[row][seg*8] = *(const u32x4*)(kbase + (size_t)row*1024 + seg*8);
      }
#pragma unroll
      for (int i = 0; i < 2; ++i) {
        int id = tid + i*256, row = id >> 3, seg = id & 7;
        *(u32x4*)&Vs[row][seg*8] = *(const u32x4*)(vbase + (size_t)row*2048 + seg*8);
      }
    }
    __syncthreads();

    // S = Q K^T : 4 j-frags x 2 k-steps
    f32x4 sc[4];
#pragma unroll
    for (int jf = 0; jf < 4; ++jf) sc[jf] = fzero();
#pragma unroll
    for (int jf = 0; jf < 4; ++jf) {
      s16x8 kb0 = *(const s16x8*)&Ks[jf*16 + lr][lg*8];
      s16x8 kb1 = *(const s16x8*)&Ks[jf*16 + lr][32 + lg*8];
      sc[jf] = mfma16(qf0, kb0, sc[jf]);
      sc[jf] = mfma16(qf1, kb1, sc[jf]);
    }

    // online softmax over j (row = lg*4+reg, col j = jf*16 + lr)
    float mnew[4], alpha[4], tsum[4];
#pragma unroll
    for (int r = 0; r < 4; ++r) {
      float mx = fmaxf(fmaxf(sc[0][r], sc[1][r]), fmaxf(sc[2][r], sc[3][r]));
#pragma unroll
      for (int off = 1; off < 16; off <<= 1) mx = fmaxf(mx, __shfl_xor(mx, off));
      mnew[r] = fmaxf(m_run[r], mx);
      alpha[r] = __expf(m_run[r] - mnew[r]);
      tsum[r] = 0.f;
    }
    unsigned short pb[4][4];
#pragma unroll
    for (int jf = 0; jf < 4; ++jf)
#pragma unroll
      for (int r = 0; r < 4; ++r) {
        float p = __expf(sc[jf][r] - mnew[r]);
        pb[jf][r] = f2bf(p);
        tsum[r] += p;
      }
#pragma unroll
    for (int r = 0; r < 4; ++r) {
#pragma unroll
      for (int off = 1; off < 16; off <<= 1) tsum[r] += __shfl_xor(tsum[r], off);
      l_run[r] = l_run[r] * alpha[r] + tsum[r];
      m_run[r] = mnew[r];
    }
#pragma unroll
    for (int d = 0; d < 4; ++d)
#pragma unroll
      for (int r = 0; r < 4; ++r) oacc[d][r] *= alpha[r];

    // P -> per-wave LDS (D-layout scatter), read back in A-fragment layout
#pragma unroll
    for (int jf = 0; jf < 4; ++jf)
#pragma unroll
      for (int r = 0; r < 4; ++r)
        Ps[w][lg*4 + r][jf*16 + lr] = pb[jf][r];

    const s16x8 pa0 = *(const s16x8*)&Ps[w][lr][lg*8];
    const s16x8 pa1 = *(const s16x8*)&Ps[w][lr][32 + lg*8];
#pragma unroll
    for (int d = 0; d < 4; ++d) {
      s16x8 vb0 = *(const s16x8*)&Vs[d*16 + lr][lg*8];
      s16x8 vb1 = *(const s16x8*)&Vs[d*16 + lr][32 + lg*8];
      oacc[d] = mfma16(pa0, vb0, oacc[d]);
      oacc[d] = mfma16(pa1, vb1, oacc[d]);
    }
  }

  // normalize and write f32 (consumed by split-precision final GEMM)
#pragma unroll
  for (int d = 0; d < 4; ++d)
#pragma unroll
    for (int r = 0; r < 4; ++r) {
      const int row = r0 + w*16 + lg*4 + r;
      const int col = h*64 + d*16 + lr;
      aout[(size_t)(b*2048 + row) * 1024 + col] = oacc[d][r] / l_run[r];
    }
}

// ---------------------------------------------------------------------------
extern "C" void kernel_launch(void* const* d_in, const int* in_sizes, int n_in,
                              void* d_out, int out_size, void* d_ws, size_t ws_size,
                              hipStream_t stream) {
  (void)in_sizes; (void)n_in; (void)out_size; (void)ws_size;
  const float* k  = (const float*)d_in[0];
  const float* q  = (const float*)d_in[1];
  const float* v  = (const float*)d_in[2];
  const float* Wk = (const float*)d_in[3];
  const float* bk = (const float*)d_in[4];
  const float* Wq = (const float*)d_in[5];
  const float* bq = (const float*)d_in[6];
  const float* Wv = (const float*)d_in[7];
  const float* bv = (const float*)d_in[8];
  const float* Wo = (const float*)d_in[9];
  const float* bo = (const float*)d_in[10];

  char* ws = (char*)d_ws;
  const size_t MB = 1024 * 1024;
  // ws layout (48 MB total):
  unsigned short* Wkt = (unsigned short*)(ws + 0*MB);    // 2 MB each
  unsigned short* Wqt = (unsigned short*)(ws + 2*MB);
  unsigned short* Wvt = (unsigned short*)(ws + 4*MB);
  unsigned short* Wot = (unsigned short*)(ws + 6*MB);
  unsigned short* kp  = (unsigned short*)(ws + 8*MB);    // 8 MB each
  unsigned short* qp  = (unsigned short*)(ws + 16*MB);
  unsigned short* vpt = (unsigned short*)(ws + 24*MB);   // transposed [b][h][d][s]
  float*          aout = (float*)(ws + 32*MB);           // 16 MB

  WArgs wa;
  wa.W[0] = Wk; wa.W[1] = Wq; wa.W[2] = Wv; wa.W[3] = Wo;
  wa.Wt[0] = Wkt; wa.Wt[1] = Wqt; wa.Wt[2] = Wvt; wa.Wt[3] = Wot;
  hipLaunchKernelGGL(wtrans_kernel, dim3(32, 32, 4), dim3(256), 0, stream, wa);

  GArgs gp;
  gp.A[0] = k;  gp.A[1] = q;  gp.A[2] = v;
  gp.Wt[0] = Wkt; gp.Wt[1] = Wqt; gp.Wt[2] = Wvt;
  gp.bias[0] = bk; gp.bias[1] = bq; gp.bias[2] = bv;
  gp.C[0] = kp; gp.C[1] = qp; gp.C[2] = vpt;
  gp.mode[0] = 0; gp.mode[1] = 0; gp.mode[2] = 1;
  hipLaunchKernelGGL(gemm_kernel, dim3(8, 32, 3), dim3(256), 0, stream, gp);

  hipLaunchKernelGGL(attn_kernel, dim3(32, 32), dim3(256), 0, stream,
                     kp, qp, vpt, aout);

  GArgs gf;
  for (int i = 0; i < 3; ++i) {
    gf.A[i] = aout; gf.Wt[i] = Wot; gf.bias[i] = bo; gf.C[i] = d_out; gf.mode[i] = 2;
  }
  hipLaunchKernelGGL(gemm_kernel, dim3(8, 32, 1), dim3(256), 0, stream, gf);
}

// Round 3
// 211.761 us; speedup vs baseline: 1.2589x; 1.2589x over previous
//
#include <hip/hip_runtime.h>
#include <hip/hip_bf16.h>
#include <stdint.h>
#include <stddef.h>

// B=2, S=2048, DM=1024, H=16, HD=64.
// out = ((k@Wk+bk) "swapped-attention" (q@Wq+bq, v@Wv+bv)) @ Wo + bo
// scores[b,c,h,q] = kp[b,c,h,:]·qp[b,q,h,:]; softmax over q; out_c = sum_q P*vp[q].

typedef __attribute__((ext_vector_type(4))) float f32x4;
typedef __attribute__((ext_vector_type(8))) short s16x8;
typedef __attribute__((ext_vector_type(4))) unsigned short u16x4;

#define DEV static __device__ __forceinline__

DEV unsigned short f2bf(float x) {              // f32 -> bf16 RNE
  unsigned int u = __float_as_uint(x);
  u += 0x7FFF + ((u >> 16) & 1);
  return (unsigned short)(u >> 16);
}
DEV f32x4 mfma16(s16x8 a, s16x8 b, f32x4 c) {
  return __builtin_amdgcn_mfma_f32_16x16x32_bf16(a, b, c, 0, 0, 0);
}
DEV f32x4 fzero() { f32x4 z; z[0]=0.f; z[1]=0.f; z[2]=0.f; z[3]=0.f; return z; }

DEV void gload_lds16(const unsigned short* g, unsigned short* l) {
  __builtin_amdgcn_global_load_lds(
      (const __attribute__((address_space(1))) unsigned int*)g,
      (__attribute__((address_space(3))) unsigned int*)l, 16, 0, 0);
}

// ---------------------------------------------------------------------------
// Kernel 0: f32 -> bf16 convert (k, q, v inputs), vectorized x4.
// ---------------------------------------------------------------------------
struct CvtArgs { const float* x[3]; unsigned short* y[3]; };

__global__ __launch_bounds__(256) void cvt_kernel(CvtArgs a) {
  const float* x = a.x[blockIdx.y];
  unsigned short* y = a.y[blockIdx.y];
  const int i = blockIdx.x * 256 + threadIdx.x;   // 4 elems each, grid exact
  f32x4 v = ((const f32x4*)x)[i];
  u16x4 o;
#pragma unroll
  for (int j = 0; j < 4; ++j) o[j] = f2bf(v[j]);
  ((u16x4*)y)[i] = o;
}

// ---------------------------------------------------------------------------
// Kernel 1: weight f32 -> bf16 transpose. W[k][n] (1024x1024) -> Wt[n][k]
// ---------------------------------------------------------------------------
struct WArgs { const float* W[4]; unsigned short* Wt[4]; };

__global__ __launch_bounds__(256) void wtrans_kernel(WArgs a) {
  const float* W = a.W[blockIdx.z];
  unsigned short* Wt = a.Wt[blockIdx.z];
  const int n0 = blockIdx.x * 32, k0 = blockIdx.y * 32;
  __shared__ float t[32][33];
  const int tx = threadIdx.x & 31, ty = threadIdx.x >> 5;
#pragma unroll
  for (int i = 0; i < 4; ++i)
    t[ty + i*8][tx] = W[(size_t)(k0 + ty + i*8) * 1024 + n0 + tx];
  __syncthreads();
#pragma unroll
  for (int i = 0; i < 4; ++i)
    Wt[(size_t)(n0 + ty + i*8) * 1024 + k0 + tx] = f2bf(t[tx][ty + i*8]);
}

// ---------------------------------------------------------------------------
// Kernel 2: bf16 GEMM  C[M][1024] = A[M][1024] @ Wt^T + bias.
// BM x 128 tile, 4 waves (2x2), BK=64, global_load_lds staging (pre-swizzled
// source), XOR-swizzled LDS (chunk ^ (row&7)) -> conflict-free ds_read_b128.
// mode 0: C bf16 row-major; mode 1: C bf16 vpt[b][h][d][s]; mode 2: C f32.
// ---------------------------------------------------------------------------
struct GemArgs {
  const unsigned short* A[3];
  const unsigned short* Wt[3];
  const float* bias[3];
  void* C[3];
  int mode[3];
};

template<int BM>
__global__ __launch_bounds__(256) void gemm_kernel(GemArgs g) {
  constexpr int MF = BM / 32;                 // A-frags per wave
  const int z = blockIdx.z;
  const unsigned short* A  = g.A[z];
  const unsigned short* Wt = g.Wt[z];
  const float* bias = g.bias[z];
  const int mode = g.mode[z];
  const int m0 = blockIdx.y * BM, n0 = blockIdx.x * 128;
  const int tid = threadIdx.x;
  const int lane = tid & 63, w = tid >> 6;
  const int wm = w >> 1, wn = w & 1;
  const int lg = lane >> 4, lr = lane & 15, lx = lr & 7;

  __shared__ __align__(16) unsigned short As[BM * 64];
  __shared__ __align__(16) unsigned short Bs[128 * 64];

  f32x4 acc[MF][4];
#pragma unroll
  for (int i = 0; i < MF; ++i)
#pragma unroll
    for (int j = 0; j < 4; ++j) acc[i][j] = fzero();

  // staging pointers (pre-swizzled global source, linear LDS dest)
  const unsigned short* srcA[MF]; unsigned short* dstA[MF];
#pragma unroll
  for (int c = 0; c < MF; ++c) {
    int n = c*256 + tid, row = n >> 3, cg = (n & 7) ^ (row & 7);
    srcA[c] = A + (size_t)(m0 + row) * 1024 + cg * 8;
    dstA[c] = &As[n * 8];
  }
  const unsigned short* srcB[4]; unsigned short* dstB[4];
#pragma unroll
  for (int c = 0; c < 4; ++c) {
    int n = c*256 + tid, row = n >> 3, cg = (n & 7) ^ (row & 7);
    srcB[c] = Wt + (size_t)(n0 + row) * 1024 + cg * 8;
    dstB[c] = &Bs[n * 8];
  }

  for (int it = 0; it < 16; ++it) {
    __syncthreads();
#pragma unroll
    for (int c = 0; c < MF; ++c) { gload_lds16(srcA[c], dstA[c]); srcA[c] += 64; }
#pragma unroll
    for (int c = 0; c < 4; ++c)  { gload_lds16(srcB[c], dstB[c]); srcB[c] += 64; }
    __syncthreads();

    s16x8 af[2][MF], bf[2][4];
#pragma unroll
    for (int ks = 0; ks < 2; ++ks) {
#pragma unroll
      for (int mf = 0; mf < MF; ++mf) {
        int row = wm*(BM/2) + mf*16 + lr;
        af[ks][mf] = *(const s16x8*)&As[row*64 + ((ks*4 + lg) ^ lx) * 8];
      }
#pragma unroll
      for (int nf = 0; nf < 4; ++nf) {
        int row = wn*64 + nf*16 + lr;
        bf[ks][nf] = *(const s16x8*)&Bs[row*64 + ((ks*4 + lg) ^ lx) * 8];
      }
    }
#pragma unroll
    for (int mf = 0; mf < MF; ++mf)
#pragma unroll
      for (int nf = 0; nf < 4; ++nf) {
        acc[mf][nf] = mfma16(af[0][mf], bf[0][nf], acc[mf][nf]);
        acc[mf][nf] = mfma16(af[1][mf], bf[1][nf], acc[mf][nf]);
      }
  }

  // epilogue: C/D layout col = lane&15, row = (lane>>4)*4 + reg
#pragma unroll
  for (int nf = 0; nf < 4; ++nf) {
    const int colg = n0 + wn*64 + nf*16 + lr;
    const float bi = bias[colg];
#pragma unroll
    for (int mf = 0; mf < MF; ++mf) {
      const int rowg0 = m0 + wm*(BM/2) + mf*16 + lg*4;
      if (mode == 0) {
        unsigned short* o = (unsigned short*)g.C[z];
#pragma unroll
        for (int r = 0; r < 4; ++r)
          o[(size_t)(rowg0 + r) * 1024 + colg] = f2bf(acc[mf][nf][r] + bi);
      } else if (mode == 1) {
        unsigned short* o = (unsigned short*)g.C[z];
        const int hh = colg >> 6, d = colg & 63;
        const int bb2 = rowg0 >> 11, s = rowg0 & 2047;
        u16x4 pk;
#pragma unroll
        for (int r = 0; r < 4; ++r) pk[r] = f2bf(acc[mf][nf][r] + bi);
        *(u16x4*)((unsigned short*)g.C[z] + ((size_t)((bb2*16 + hh)*64 + d)) * 2048 + s) = pk;
        (void)o;
      } else {
        float* o = (float*)g.C[z];
#pragma unroll
        for (int r = 0; r < 4; ++r)
          o[(size_t)(rowg0 + r) * 1024 + colg] = acc[mf][nf][r] + bi;
      }
    }
  }
}

// ---------------------------------------------------------------------------
// Kernel 3: flash attention (swapped roles), 64 c-rows/block, 4 waves x 16.
// Combined KV LDS tile [64 rows][16 chunks of 16B]: chunks 0-7 = K row j,
// chunks 8-15 = V row d. XOR swizzle (low 3 bits of chunk ^ row&7), staged
// with global_load_lds from pre-swizzled per-lane source. Defer-max softmax.
// Output bf16.
// ---------------------------------------------------------------------------
__global__ __launch_bounds__(256) void attn_kernel(
    const unsigned short* __restrict__ kp, const unsigned short* __restrict__ qp,
    const unsigned short* __restrict__ vpt, unsigned short* __restrict__ aout) {
  const int bh = blockIdx.y, b = bh >> 4, h = bh & 15;
  const int r0 = blockIdx.x * 64;
  const int tid = threadIdx.x, lane = tid & 63, w = tid >> 6;
  const int lg = lane >> 4, lr = lane & 15, lx = lr & 7;

  __shared__ __align__(16) unsigned short KV[64 * 128];   // 16 KB
  __shared__ __align__(16) unsigned short Ps[4][16 * 64]; // per-wave 2 KB

  // Q fragments (A-operand rows = c-rows from kp)
  const unsigned short* qptr =
      kp + (size_t)(b*2048 + r0 + w*16 + lr) * 1024 + h*64 + lg*8;
  const s16x8 qf0 = *(const s16x8*)qptr;
  const s16x8 qf1 = *(const s16x8*)(qptr + 32);

  const unsigned short* kbase = qp + (size_t)(b*2048) * 1024 + h*64;   // row stride 1024
  const unsigned short* vbase = vpt + (size_t)((b*16 + h) * 64) * 2048; // row stride 2048

  const unsigned short* src[4]; unsigned short* dst[4]; int stp[4];
#pragma unroll
  for (int c = 0; c < 4; ++c) {
    int n = c*256 + tid, row = n >> 4, cg = (n & 15) ^ (row & 7);
    bool isK = cg < 8;
    src[c] = isK ? kbase + (size_t)row * 1024 + cg * 8
                 : vbase + (size_t)row * 2048 + (cg - 8) * 8;
    stp[c] = isK ? 65536 : 64;            // K: +64 rows; V: +64 cols
    dst[c] = &KV[n * 8];
  }

  float m_run[4], l_run[4];
  f32x4 oacc[4];
#pragma unroll
  for (int r = 0; r < 4; ++r) { m_run[r] = -1e30f; l_run[r] = 0.f; }
#pragma unroll
  for (int d = 0; d < 4; ++d) oacc[d] = fzero();

  for (int jt = 0; jt < 32; ++jt) {
    __syncthreads();
#pragma unroll
    for (int c = 0; c < 4; ++c) { gload_lds16(src[c], dst[c]); src[c] += stp[c]; }
    __syncthreads();

    // S = Q K^T
    f32x4 sc[4];
#pragma unroll
    for (int jf = 0; jf < 4; ++jf) sc[jf] = fzero();
#pragma unroll
    for (int jf = 0; jf < 4; ++jf) {
      const unsigned short* krow = &KV[(jf*16 + lr) * 128];
      sc[jf] = mfma16(qf0, *(const s16x8*)&krow[((lg) ^ lx) * 8], sc[jf]);
      sc[jf] = mfma16(qf1, *(const s16x8*)&krow[((4 + lg) ^ lx) * 8], sc[jf]);
    }

    // online softmax over j (row c = lg*4+r, col j = jf*16+lr), defer-max THR=8
    float mx[4];
#pragma unroll
    for (int r = 0; r < 4; ++r) {
      mx[r] = fmaxf(fmaxf(sc[0][r], sc[1][r]), fmaxf(sc[2][r], sc[3][r]));
#pragma unroll
      for (int off = 1; off < 16; off <<= 1) mx[r] = fmaxf(mx[r], __shfl_xor(mx[r], off));
    }
    bool grow = false;
#pragma unroll
    for (int r = 0; r < 4; ++r) grow = grow || (mx[r] > m_run[r] + 8.0f);
    if (__any(grow)) {
#pragma unroll
      for (int r = 0; r < 4; ++r) {
        float mn = fmaxf(m_run[r], mx[r]);
        float al = __expf(m_run[r] - mn);
        m_run[r] = mn; l_run[r] *= al;
#pragma unroll
        for (int d = 0; d < 4; ++d) oacc[d][r] *= al;
      }
    }
    float ts[4]; unsigned short pb[4][4];
#pragma unroll
    for (int r = 0; r < 4; ++r) ts[r] = 0.f;
#pragma unroll
    for (int jf = 0; jf < 4; ++jf)
#pragma unroll
      for (int r = 0; r < 4; ++r) {
        float p = __expf(sc[jf][r] - m_run[r]);   // bounded by e^8
        pb[jf][r] = f2bf(p);
        ts[r] += p;
      }
#pragma unroll
    for (int r = 0; r < 4; ++r) {
#pragma unroll
      for (int off = 1; off < 16; off <<= 1) ts[r] += __shfl_xor(ts[r], off);
      l_run[r] += ts[r];
    }

    // P -> per-wave LDS (swizzled), read back as A-fragments
    unsigned short* pw = Ps[w];
#pragma unroll
    for (int jf = 0; jf < 4; ++jf)
#pragma unroll
      for (int r = 0; r < 4; ++r) {
        int prow = lg*4 + r;
        pw[prow*64 + ((jf*2 + (lr >> 3)) ^ (prow & 7)) * 8 + (lr & 7)] = pb[jf][r];
      }
    const s16x8 pa0 = *(const s16x8*)&pw[lr*64 + ((lg) ^ lx) * 8];
    const s16x8 pa1 = *(const s16x8*)&pw[lr*64 + ((4 + lg) ^ lx) * 8];

#pragma unroll
    for (int d = 0; d < 4; ++d) {
      const unsigned short* vrow = &KV[(d*16 + lr) * 128];
      oacc[d] = mfma16(pa0, *(const s16x8*)&vrow[((8 + lg) ^ lx) * 8], oacc[d]);
      oacc[d] = mfma16(pa1, *(const s16x8*)&vrow[((12 + lg) ^ lx) * 8], oacc[d]);
    }
  }

  // normalize, write bf16 (consumed by final GEMM)
  const size_t obase = (size_t)(b*2048 + r0 + w*16) * 1024 + h*64;
#pragma unroll
  for (int r = 0; r < 4; ++r) {
    const float inv = 1.0f / l_run[r];
#pragma unroll
    for (int d = 0; d < 4; ++d)
      aout[obase + (size_t)(lg*4 + r) * 1024 + d*16 + lr] = f2bf(oacc[d][r] * inv);
  }
}

// ---------------------------------------------------------------------------
extern "C" void kernel_launch(void* const* d_in, const int* in_sizes, int n_in,
                              void* d_out, int out_size, void* d_ws, size_t ws_size,
                              hipStream_t stream) {
  (void)in_sizes; (void)n_in; (void)out_size; (void)ws_size;
  const float* k  = (const float*)d_in[0];
  const float* q  = (const float*)d_in[1];
  const float* v  = (const float*)d_in[2];
  const float* Wk = (const float*)d_in[3];
  const float* bk = (const float*)d_in[4];
  const float* Wq = (const float*)d_in[5];
  const float* bq = (const float*)d_in[6];
  const float* Wv = (const float*)d_in[7];
  const float* bv = (const float*)d_in[8];
  const float* Wo = (const float*)d_in[9];
  const float* bo = (const float*)d_in[10];

  char* ws = (char*)d_ws;
  const size_t MB = 1024 * 1024;
  // ws layout (48 MB): weights 0-8, kp 8-16, qp 16-24, vpt 24-32, vc 32-40, aout 40-48
  unsigned short* Wkt = (unsigned short*)(ws + 0*MB);
  unsigned short* Wqt = (unsigned short*)(ws + 2*MB);
  unsigned short* Wvt = (unsigned short*)(ws + 4*MB);
  unsigned short* Wot = (unsigned short*)(ws + 6*MB);
  unsigned short* kp  = (unsigned short*)(ws + 8*MB);
  unsigned short* qp  = (unsigned short*)(ws + 16*MB);
  unsigned short* vpt = (unsigned short*)(ws + 24*MB);
  unsigned short* vc  = (unsigned short*)(ws + 32*MB);
  unsigned short* aoutb = (unsigned short*)(ws + 40*MB);
  // transient bf16 activations in d_out (16 MB f32 buffer; overwritten at end)
  unsigned short* kc = (unsigned short*)d_out;
  unsigned short* qc = (unsigned short*)((char*)d_out + 8*MB);

  CvtArgs ca;
  ca.x[0] = k; ca.x[1] = q; ca.x[2] = v;
  ca.y[0] = kc; ca.y[1] = qc; ca.y[2] = vc;
  cvt_kernel<<<dim3(4096, 3), 256, 0, stream>>>(ca);

  WArgs wa;
  wa.W[0] = Wk; wa.W[1] = Wq; wa.W[2] = Wv; wa.W[3] = Wo;
  wa.Wt[0] = Wkt; wa.Wt[1] = Wqt; wa.Wt[2] = Wvt; wa.Wt[3] = Wot;
  wtrans_kernel<<<dim3(32, 32, 4), 256, 0, stream>>>(wa);

  GemArgs gp;
  gp.A[0] = kc; gp.A[1] = qc; gp.A[2] = vc;
  gp.Wt[0] = Wkt; gp.Wt[1] = Wqt; gp.Wt[2] = Wvt;
  gp.bias[0] = bk; gp.bias[1] = bq; gp.bias[2] = bv;
  gp.C[0] = kp; gp.C[1] = qp; gp.C[2] = vpt;
  gp.mode[0] = 0; gp.mode[1] = 0; gp.mode[2] = 1;
  gemm_kernel<128><<<dim3(8, 32, 3), 256, 0, stream>>>(gp);

  attn_kernel<<<dim3(32, 32), 256, 0, stream>>>(kp, qp, vpt, aoutb);

  GemArgs gf;
  gf.A[0] = aoutb; gf.A[1] = aoutb; gf.A[2] = aoutb;
  gf.Wt[0] = Wot; gf.Wt[1] = Wot; gf.Wt[2] = Wot;
  gf.bias[0] = bo; gf.bias[1] = bo; gf.bias[2] = bo;
  gf.C[0] = d_out; gf.C[1] = d_out; gf.C[2] = d_out;
  gf.mode[0] = 2; gf.mode[1] = 2; gf.mode[2] = 2;
  gemm_kernel<64><<<dim3(8, 64, 1), 256, 0, stream>>>(gf);
}

// Round 4
// 207.599 us; speedup vs baseline: 1.2841x; 1.0200x over previous
//
#include <hip/hip_runtime.h>
#include <hip/hip_bf16.h>
#include <stdint.h>
#include <stddef.h>

// B=2, S=2048, DM=1024, H=16, HD=64.
// out = ((k@Wk+bk) "swapped-attention" (q@Wq+bq, v@Wv+bv)) @ Wo + bo
// scores[b,c,h,q] = kp[b,c,h,:]·qp[b,q,h,:]; softmax over q; out_c = sum_q P*vp[q].

typedef __attribute__((ext_vector_type(4))) float f32x4;
typedef __attribute__((ext_vector_type(16))) float f32x16;
typedef __attribute__((ext_vector_type(8))) short s16x8;
typedef __attribute__((ext_vector_type(4))) unsigned int u32x4;
typedef __attribute__((ext_vector_type(4))) unsigned short u16x4;

#define DEV static __device__ __forceinline__

DEV unsigned short f2bf(float x) {              // f32 -> bf16 RNE
  unsigned int u = __float_as_uint(x);
  u += 0x7FFF + ((u >> 16) & 1);
  return (unsigned short)(u >> 16);
}
DEV f32x4 mfma16(s16x8 a, s16x8 b, f32x4 c) {
  return __builtin_amdgcn_mfma_f32_16x16x32_bf16(a, b, c, 0, 0, 0);
}
DEV f32x16 mfma32(s16x8 a, s16x8 b, f32x16 c) {
  return __builtin_amdgcn_mfma_f32_32x32x16_bf16(a, b, c, 0, 0, 0);
}
DEV f32x4 fzero() { f32x4 z; z[0]=0.f; z[1]=0.f; z[2]=0.f; z[3]=0.f; return z; }
DEV f32x16 fzero16() {
  f32x16 z;
#pragma unroll
  for (int i = 0; i < 16; ++i) z[i] = 0.f;
  return z;
}

DEV void gload_lds16(const unsigned short* g, unsigned short* l) {
  __builtin_amdgcn_global_load_lds(
      (const __attribute__((address_space(1))) unsigned int*)g,
      (__attribute__((address_space(3))) unsigned int*)l, 16, 0, 0);
}

#define CVTPK(dst, a, b) \
  asm("v_cvt_pk_bf16_f32 %0, %1, %2" : "=v"(dst) : "v"(a), "v"(b))
#define PSWAP(x, y) \
  asm("v_permlane32_swap_b32 %0, %1" : "+v"(x), "+v"(y))

// ---------------------------------------------------------------------------
// Kernel 0: f32 -> bf16 convert (k, q, v inputs), vectorized x4.
// ---------------------------------------------------------------------------
struct CvtArgs { const float* x[3]; unsigned short* y[3]; };

__global__ __launch_bounds__(256) void cvt_kernel(CvtArgs a) {
  const float* x = a.x[blockIdx.y];
  unsigned short* y = a.y[blockIdx.y];
  const int i = blockIdx.x * 256 + threadIdx.x;
  f32x4 v = ((const f32x4*)x)[i];
  u16x4 o;
#pragma unroll
  for (int j = 0; j < 4; ++j) o[j] = f2bf(v[j]);
  ((u16x4*)y)[i] = o;
}

// ---------------------------------------------------------------------------
// Kernel 1: weight f32 -> bf16 transpose. W[k][n] (1024x1024) -> Wt[n][k]
// ---------------------------------------------------------------------------
struct WArgs { const float* W[4]; unsigned short* Wt[4]; };

__global__ __launch_bounds__(256) void wtrans_kernel(WArgs a) {
  const float* W = a.W[blockIdx.z];
  unsigned short* Wt = a.Wt[blockIdx.z];
  const int n0 = blockIdx.x * 32, k0 = blockIdx.y * 32;
  __shared__ float t[32][33];
  const int tx = threadIdx.x & 31, ty = threadIdx.x >> 5;
#pragma unroll
  for (int i = 0; i < 4; ++i)
    t[ty + i*8][tx] = W[(size_t)(k0 + ty + i*8) * 1024 + n0 + tx];
  __syncthreads();
#pragma unroll
  for (int i = 0; i < 4; ++i)
    Wt[(size_t)(n0 + ty + i*8) * 1024 + k0 + tx] = f2bf(t[tx][ty + i*8]);
}

// ---------------------------------------------------------------------------
// Kernel 2: bf16 GEMM  C[M][1024] = A[M][1024] @ Wt^T + bias.
// BM x 128 tile, 4 waves (2x2), BK=64, global_load_lds staging (pre-swizzled
// source), XOR-swizzled LDS -> conflict-free ds_read_b128.
// mode 0: C bf16 row-major; mode 1: C bf16 vpt[b][h][d][s]; mode 2: C f32,
//         A read from aout_h layout [b][h][s][64].
// ---------------------------------------------------------------------------
struct GemArgs {
  const unsigned short* A[3];
  const unsigned short* Wt[3];
  const float* bias[3];
  void* C[3];
  int mode[3];
};

template<int BM>
__global__ __launch_bounds__(256) void gemm_kernel(GemArgs g) {
  constexpr int MF = BM / 32;
  const int z = blockIdx.z;
  const unsigned short* A  = g.A[z];
  const unsigned short* Wt = g.Wt[z];
  const float* bias = g.bias[z];
  const int mode = g.mode[z];
  const int m0 = blockIdx.y * BM, n0 = blockIdx.x * 128;
  const int tid = threadIdx.x;
  const int lane = tid & 63, w = tid >> 6;
  const int wm = w >> 1, wn = w & 1;
  const int lg = lane >> 4, lr = lane & 15, lx = lr & 7;

  __shared__ __align__(16) unsigned short As[BM * 64];
  __shared__ __align__(16) unsigned short Bs[128 * 64];

  f32x4 acc[MF][4];
#pragma unroll
  for (int i = 0; i < MF; ++i)
#pragma unroll
    for (int j = 0; j < 4; ++j) acc[i][j] = fzero();

  const int aStep = (mode == 2) ? 2048 * 64 : 64;
  const unsigned short* srcA[MF]; unsigned short* dstA[MF];
#pragma unroll
  for (int c = 0; c < MF; ++c) {
    int n = c*256 + tid, row = n >> 3, cg = (n & 7) ^ (row & 7);
    int s = m0 + row;
    size_t abase = (mode == 2)
        ? ((size_t)((s >> 11) * 16) * 2048 + (s & 2047)) * 64 + cg * 8
        : (size_t)s * 1024 + cg * 8;
    srcA[c] = A + abase;
    dstA[c] = &As[n * 8];
  }
  const unsigned short* srcB[4]; unsigned short* dstB[4];
#pragma unroll
  for (int c = 0; c < 4; ++c) {
    int n = c*256 + tid, row = n >> 3, cg = (n & 7) ^ (row & 7);
    srcB[c] = Wt + (size_t)(n0 + row) * 1024 + cg * 8;
    dstB[c] = &Bs[n * 8];
  }

  for (int it = 0; it < 16; ++it) {
    __syncthreads();
#pragma unroll
    for (int c = 0; c < MF; ++c) { gload_lds16(srcA[c], dstA[c]); srcA[c] += aStep; }
#pragma unroll
    for (int c = 0; c < 4; ++c)  { gload_lds16(srcB[c], dstB[c]); srcB[c] += 64; }
    __syncthreads();

    s16x8 af[2][MF], bf[2][4];
#pragma unroll
    for (int ks = 0; ks < 2; ++ks) {
#pragma unroll
      for (int mf = 0; mf < MF; ++mf) {
        int row = wm*(BM/2) + mf*16 + lr;
        af[ks][mf] = *(const s16x8*)&As[row*64 + ((ks*4 + lg) ^ lx) * 8];
      }
#pragma unroll
      for (int nf = 0; nf < 4; ++nf) {
        int row = wn*64 + nf*16 + lr;
        bf[ks][nf] = *(const s16x8*)&Bs[row*64 + ((ks*4 + lg) ^ lx) * 8];
      }
    }
#pragma unroll
    for (int mf = 0; mf < MF; ++mf)
#pragma unroll
      for (int nf = 0; nf < 4; ++nf) {
        acc[mf][nf] = mfma16(af[0][mf], bf[0][nf], acc[mf][nf]);
        acc[mf][nf] = mfma16(af[1][mf], bf[1][nf], acc[mf][nf]);
      }
  }

#pragma unroll
  for (int nf = 0; nf < 4; ++nf) {
    const int colg = n0 + wn*64 + nf*16 + lr;
    const float bi = bias[colg];
#pragma unroll
    for (int mf = 0; mf < MF; ++mf) {
      const int rowg0 = m0 + wm*(BM/2) + mf*16 + lg*4;
      if (mode == 0) {
        unsigned short* o = (unsigned short*)g.C[z];
#pragma unroll
        for (int r = 0; r < 4; ++r)
          o[(size_t)(rowg0 + r) * 1024 + colg] = f2bf(acc[mf][nf][r] + bi);
      } else if (mode == 1) {
        const int hh = colg >> 6, d = colg & 63;
        const int bb2 = rowg0 >> 11, s = rowg0 & 2047;
        u16x4 pk;
#pragma unroll
        for (int r = 0; r < 4; ++r) pk[r] = f2bf(acc[mf][nf][r] + bi);
        *(u16x4*)((unsigned short*)g.C[z] + ((size_t)((bb2*16 + hh)*64 + d)) * 2048 + s) = pk;
      } else {
        float* o = (float*)g.C[z];
#pragma unroll
        for (int r = 0; r < 4; ++r)
          o[(size_t)(rowg0 + r) * 1024 + colg] = acc[mf][nf][r] + bi;
      }
    }
  }
}

// ---------------------------------------------------------------------------
// Kernel 3: zero-LDS flash attention, swapped-operand 32x32x16 MFMA.
// Block = 128 thr (2 waves), each wave: 32 c-rows x 1024 j (half range),
// merge partials through LDS at the end.  S^T = mfma(A=qp_j, B=kp_c):
// lane owns col c = lane&31, 16 j-rows; softmax = reg-reduce + shfl_xor(32).
// P -> PV B-operand via cvt_pk_bf16 + permlane32_swap.  PV: out[d][c] =
// mfma(A=vpt_d, B=P^T); lane's 32 out-regs all share its c.
// Output layout aout_h[b][h][s][64] bf16.
// ---------------------------------------------------------------------------
__global__ __launch_bounds__(128) void attn_kernel(
    const unsigned short* __restrict__ kp, const unsigned short* __restrict__ qp,
    const unsigned short* __restrict__ vpt, unsigned short* __restrict__ aout) {
  const int bh = blockIdx.y, b = bh >> 4, h = bh & 15;
  const int c0 = blockIdx.x * 32;
  const int tid = threadIdx.x, lane = tid & 63, w = tid >> 6;
  const int ln = lane & 31, hh = lane >> 5;

  __shared__ float obuf[32][64];
  __shared__ float mbuf[64], lbuf[64];

  const unsigned short* qbh = qp + (size_t)(b*2048) * 1024 + h*64 + hh*8;
  const unsigned short* kbh = kp + (size_t)(b*2048) * 1024 + h*64 + hh*8;
  const unsigned short* vrow =
      vpt + ((size_t)((b*16 + h) * 64) + ln) * 2048 + hh*8;

  // kp B-fragments: fixed for the whole kernel (c = c0 + ln)
  s16x8 kb[4];
  {
    const unsigned short* krow = kbh + (size_t)(c0 + ln) * 1024;
#pragma unroll
    for (int s = 0; s < 4; ++s) kb[s] = *(const s16x8*)(krow + s*16);
  }

  const int wbase = w * 1024;

  f32x16 acc0 = fzero16(), acc1 = fzero16();
  float m_run = -1e30f, l_run = 0.f;

  s16x8 qaA[4], qaB[4];
  {
    const unsigned short* qrow = qbh + (size_t)(wbase + ln) * 1024;
#pragma unroll
    for (int s = 0; s < 4; ++s) qaA[s] = *(const s16x8*)(qrow + s*16);
  }

#define LOAD_QA(dst, tidx)                                                    \
  {                                                                           \
    const unsigned short* qrow = qbh + (size_t)(wbase + (tidx)*32 + ln) * 1024;\
    _Pragma("unroll")                                                         \
    for (int s = 0; s < 4; ++s) dst[s] = *(const s16x8*)(qrow + s*16);        \
  }

#define ATTN_TILE(JT, QA)                                                     \
  {                                                                           \
    const int j0t = wbase + (JT)*32;                                          \
    s16x8 vb[4];                                                              \
    _Pragma("unroll")                                                         \
    for (int t = 0; t < 4; ++t)                                               \
      vb[t] = *(const s16x8*)(vrow + (size_t)(t >> 1)*32*2048 + j0t + (t & 1)*16); \
    f32x16 sc = fzero16();                                                    \
    _Pragma("unroll")                                                         \
    for (int s = 0; s < 4; ++s) sc = mfma32(QA[s], kb[s], sc);                \
    float mx = sc[0];                                                         \
    _Pragma("unroll")                                                         \
    for (int r = 1; r < 16; ++r) mx = fmaxf(mx, sc[r]);                       \
    mx = fmaxf(mx, __shfl_xor(mx, 32));                                       \
    if (__any(mx > m_run + 8.0f)) {                                           \
      float mn = fmaxf(m_run, mx);                                            \
      float al = __expf(m_run - mn);                                          \
      m_run = mn; l_run *= al;                                                \
      _Pragma("unroll")                                                       \
      for (int r = 0; r < 16; ++r) { acc0[r] *= al; acc1[r] *= al; }          \
    }                                                                         \
    float ts = 0.f;                                                           \
    _Pragma("unroll")                                                         \
    for (int r = 0; r < 16; ++r) {                                            \
      float p = __expf(sc[r] - m_run); sc[r] = p; ts += p;                    \
    }                                                                         \
    ts += __shfl_xor(ts, 32);                                                 \
    l_run += ts;                                                              \
    unsigned int a0, a1, b0, b1;                                              \
    u32x4 wv; s16x8 pa0, pa1;                                                 \
    CVTPK(a0, sc[0], sc[1]);  CVTPK(b0, sc[4], sc[5]);  PSWAP(a0, b0);        \
    CVTPK(a1, sc[2], sc[3]);  CVTPK(b1, sc[6], sc[7]);  PSWAP(a1, b1);        \
    wv[0] = a0; wv[1] = a1; wv[2] = b0; wv[3] = b1;                           \
    pa0 = __builtin_bit_cast(s16x8, wv);                                      \
    CVTPK(a0, sc[8], sc[9]);  CVTPK(b0, sc[12], sc[13]); PSWAP(a0, b0);       \
    CVTPK(a1, sc[10], sc[11]); CVTPK(b1, sc[14], sc[15]); PSWAP(a1, b1);      \
    wv[0] = a0; wv[1] = a1; wv[2] = b0; wv[3] = b1;                           \
    pa1 = __builtin_bit_cast(s16x8, wv);                                      \
    acc0 = mfma32(vb[0], pa0, acc0);                                          \
    acc0 = mfma32(vb[1], pa1, acc0);                                          \
    acc1 = mfma32(vb[2], pa0, acc1);                                          \
    acc1 = mfma32(vb[3], pa1, acc1);                                          \
  }

  for (int jt = 0; jt < 32; jt += 2) {
    LOAD_QA(qaB, (jt + 1 < 32 ? jt + 1 : 31));
    ATTN_TILE(jt, qaA);
    LOAD_QA(qaA, (jt + 2 < 32 ? jt + 2 : 31));
    ATTN_TILE(jt + 1, qaB);
  }
#undef ATTN_TILE
#undef LOAD_QA

  // merge the two waves' partials (flash-decoding style)
  if (w == 1) {
    mbuf[lane] = m_run; lbuf[lane] = l_run;
#pragma unroll
    for (int r = 0; r < 16; ++r) { obuf[r][lane] = acc0[r]; obuf[16 + r][lane] = acc1[r]; }
  }
  __syncthreads();
  if (w == 0) {
    const float m1 = mbuf[lane], l1 = lbuf[lane];
    const float mt = fmaxf(m_run, m1);
    float a0 = __expf(m_run - mt), a1 = __expf(m1 - mt);
    const float inv = 1.0f / (a0 * l_run + a1 * l1);
    a0 *= inv; a1 *= inv;
    unsigned short* obase =
        aout + ((size_t)(bh) * 2048 + c0 + ln) * 64 + hh * 4;
#pragma unroll
    for (int dt = 0; dt < 2; ++dt)
#pragma unroll
      for (int rq = 0; rq < 4; ++rq) {
        u16x4 pk;
#pragma unroll
        for (int i = 0; i < 4; ++i) {
          int reg = rq*4 + i;
          float own = (dt == 0) ? acc0[reg] : acc1[reg];
          float oth = obuf[dt*16 + reg][lane];
          pk[i] = f2bf(a0 * own + a1 * oth);
        }
        *(u16x4*)(obase + dt*32 + rq*8) = pk;
      }
  }
}

// ---------------------------------------------------------------------------
extern "C" void kernel_launch(void* const* d_in, const int* in_sizes, int n_in,
                              void* d_out, int out_size, void* d_ws, size_t ws_size,
                              hipStream_t stream) {
  (void)in_sizes; (void)n_in; (void)out_size; (void)ws_size;
  const float* k  = (const float*)d_in[0];
  const float* q  = (const float*)d_in[1];
  const float* v  = (const float*)d_in[2];
  const float* Wk = (const float*)d_in[3];
  const float* bk = (const float*)d_in[4];
  const float* Wq = (const float*)d_in[5];
  const float* bq = (const float*)d_in[6];
  const float* Wv = (const float*)d_in[7];
  const float* bv = (const float*)d_in[8];
  const float* Wo = (const float*)d_in[9];
  const float* bo = (const float*)d_in[10];

  char* ws = (char*)d_ws;
  const size_t MB = 1024 * 1024;
  unsigned short* Wkt = (unsigned short*)(ws + 0*MB);
  unsigned short* Wqt = (unsigned short*)(ws + 2*MB);
  unsigned short* Wvt = (unsigned short*)(ws + 4*MB);
  unsigned short* Wot = (unsigned short*)(ws + 6*MB);
  unsigned short* kp  = (unsigned short*)(ws + 8*MB);
  unsigned short* qp  = (unsigned short*)(ws + 16*MB);
  unsigned short* vpt = (unsigned short*)(ws + 24*MB);
  unsigned short* vc  = (unsigned short*)(ws + 32*MB);
  unsigned short* aoutb = (unsigned short*)(ws + 40*MB);  // [b][h][s][64] bf16
  unsigned short* kc = (unsigned short*)d_out;
  unsigned short* qc = (unsigned short*)((char*)d_out + 8*MB);

  CvtArgs ca;
  ca.x[0] = k; ca.x[1] = q; ca.x[2] = v;
  ca.y[0] = kc; ca.y[1] = qc; ca.y[2] = vc;
  cvt_kernel<<<dim3(4096, 3), 256, 0, stream>>>(ca);

  WArgs wa;
  wa.W[0] = Wk; wa.W[1] = Wq; wa.W[2] = Wv; wa.W[3] = Wo;
  wa.Wt[0] = Wkt; wa.Wt[1] = Wqt; wa.Wt[2] = Wvt; wa.Wt[3] = Wot;
  wtrans_kernel<<<dim3(32, 32, 4), 256, 0, stream>>>(wa);

  GemArgs gp;
  gp.A[0] = kc; gp.A[1] = qc; gp.A[2] = vc;
  gp.Wt[0] = Wkt; gp.Wt[1] = Wqt; gp.Wt[2] = Wvt;
  gp.bias[0] = bk; gp.bias[1] = bq; gp.bias[2] = bv;
  gp.C[0] = kp; gp.C[1] = qp; gp.C[2] = vpt;
  gp.mode[0] = 0; gp.mode[1] = 0; gp.mode[2] = 1;
  gemm_kernel<128><<<dim3(8, 32, 3), 256, 0, stream>>>(gp);

  attn_kernel<<<dim3(64, 32), 128, 0, stream>>>(kp, qp, vpt, aoutb);

  GemArgs gf;
  gf.A[0] = aoutb; gf.A[1] = aoutb; gf.A[2] = aoutb;
  gf.Wt[0] = Wot; gf.Wt[1] = Wot; gf.Wt[2] = Wot;
  gf.bias[0] = bo; gf.bias[1] = bo; gf.bias[2] = bo;
  gf.C[0] = d_out; gf.C[1] = d_out; gf.C[2] = d_out;
  gf.mode[0] = 2; gf.mode[1] = 2; gf.mode[2] = 2;
  gemm_kernel<64><<<dim3(8, 64, 1), 256, 0, stream>>>(gf);
}